// Round 6
// baseline (229.717 us; speedup 1.0000x reference)
//
#include <hip/hip_runtime.h>
#include <hip/hip_fp16.h>
#include <string.h>

#define DIM 256

typedef __attribute__((ext_vector_type(2))) _Float16 half2v;

#if defined(__has_builtin)
#if __has_builtin(__builtin_amdgcn_fdot2)
#define HAVE_FDOT2 1
#endif
#endif

// ---------- fp32 -> fp16 compression with (re,im) pair interleave --------------
// Output row layout: pair j at halves [2j, 2j+1] = (in[j], in[j+128]).
// 32 threads per row; thread q handles pairs [4q, 4q+4): reads float4 from the
// real half at elems [4q..4q+4) and float4 from the imag half at [128+4q..),
// writes one int4 (4 half2 pairs). All loads/stores coalesced.
__global__ __launch_bounds__(256) void f32_to_f16i_kernel(
    const float* __restrict__ in, int4* __restrict__ out, int nrows)
{
    int i = blockIdx.x * blockDim.x + threadIdx.x;
    int row = i >> 5;
    int q   = i & 31;
    if (row >= nrows) return;

    const float4* re = (const float4*)(in + (size_t)row * DIM) + q;
    const float4* im = (const float4*)(in + (size_t)row * DIM + 128) + q;
    float4 a = *re;
    float4 b = *im;

    __half2 p0 = __float22half2_rn(make_float2(a.x, b.x));
    __half2 p1 = __float22half2_rn(make_float2(a.y, b.y));
    __half2 p2 = __float22half2_rn(make_float2(a.z, b.z));
    __half2 p3 = __float22half2_rn(make_float2(a.w, b.w));

    int4 o;
    memcpy(&o.x, &p0, 4);
    memcpy(&o.y, &p1, 4);
    memcpy(&o.z, &p2, 4);
    memcpy(&o.w, &p3, 4);
    out[(size_t)row * 32 + q] = o;
}

// ---------- per-pair score term ------------------------------------------------
// h2=(rh,ih), t2=(rt,it), r2=(rr,ir), all fp16 pairs in one u32.
//   u = rr*rt + ir*it            = dot2(r2, t2)
//   v = rr*it - ir*rt            = dot2(r2, (it, -rt))
//   acc += rh*u + ih*v
__device__ __forceinline__ float pair_term(int h32, int t32, int r32, float acc)
{
    unsigned tu = (unsigned)t32;
    unsigned tsw = (tu >> 16) | ((tu << 16) ^ 0x80000000u);  // (it, -rt)

    half2v h2, t2, r2, ts2;
    memcpy(&h2, &h32, 4);
    memcpy(&t2, &t32, 4);
    memcpy(&r2, &r32, 4);
    memcpy(&ts2, &tsw, 4);

#ifdef HAVE_FDOT2
    float u = __builtin_amdgcn_fdot2(r2, t2, 0.0f, false);
    float v = __builtin_amdgcn_fdot2(r2, ts2, 0.0f, false);
#else
    float rr = (float)r2.x, ir = (float)r2.y;
    float rt = (float)t2.x, it = (float)t2.y;
    float u = rr * rt + ir * it;
    float v = rr * it - ir * rt;
    (void)ts2;
#endif
    float rh = (float)h2.x;
    float ih = (float)h2.y;
    acc = fmaf(rh, u, acc);
    acc = fmaf(ih, v, acc);
    return acc;
}

// ---------- main gather/score kernel on interleaved fp16 rows ------------------
// 32 lanes per edge; lane l holds pairs [4l, 4l+4) of each row (one int4 each).
// No cross-lane exchange needed; only the final 32-lane sum reduction.
__global__ __launch_bounds__(256) void complex_score_f16i_kernel(
    const __half* __restrict__ node,
    const __half* __restrict__ rel,
    const int* __restrict__ src,
    const int* __restrict__ dst,
    const int* __restrict__ rid,
    float* __restrict__ out,
    int n_edges)
{
    const int tid  = blockIdx.x * blockDim.x + threadIdx.x;
    const int edge = tid >> 5;
    const int lane = tid & 31;
    if (edge >= n_edges) return;

    const int s = src[edge];
    const int d = dst[edge];
    const int r = rid[edge];

    const int4* hp = (const int4*)(node + (size_t)s * DIM);
    const int4* tp = (const int4*)(node + (size_t)d * DIM);
    const int4* rp = (const int4*)(rel  + (size_t)r * DIM);

    int4 hv = hp[lane];
    int4 tv = tp[lane];
    int4 rv = rp[lane];

    float acc = 0.0f;
    acc = pair_term(hv.x, tv.x, rv.x, acc);
    acc = pair_term(hv.y, tv.y, rv.y, acc);
    acc = pair_term(hv.z, tv.z, rv.z, acc);
    acc = pair_term(hv.w, tv.w, rv.w, acc);

    #pragma unroll
    for (int off = 16; off > 0; off >>= 1)
        acc += __shfl_xor(acc, off);

    if (lane == 0)
        out[edge] = acc;
}

// ---------- fallback: direct fp32 path (if ws is too small) --------------------
__global__ __launch_bounds__(256) void complex_score_f32_kernel(
    const float* __restrict__ node_emb,
    const float* __restrict__ rel_emb,
    const int* __restrict__ src,
    const int* __restrict__ dst,
    const int* __restrict__ rel_id,
    float* __restrict__ out,
    int n_edges)
{
    const int tid  = blockIdx.x * blockDim.x + threadIdx.x;
    const int edge = tid >> 5;
    const int lane = tid & 31;
    if (edge >= n_edges) return;

    const int s = src[edge];
    const int d = dst[edge];
    const int r = rel_id[edge];

    const float4* hp = (const float4*)(node_emb + (size_t)s * DIM);
    const float4* tp = (const float4*)(node_emb + (size_t)d * DIM);
    const float4* rp = (const float4*)(rel_emb  + (size_t)r * DIM);

    float4 rh = hp[lane];
    float4 ih = hp[lane + 32];
    float4 rt = tp[lane];
    float4 it = tp[lane + 32];
    float4 rr = rp[lane];
    float4 ir = rp[lane + 32];

    float a0 = rr.x * (rh.x * rt.x + ih.x * it.x) + ir.x * (rh.x * it.x - ih.x * rt.x);
    float a1 = rr.y * (rh.y * rt.y + ih.y * it.y) + ir.y * (rh.y * it.y - ih.y * rt.y);
    float a2 = rr.z * (rh.z * rt.z + ih.z * it.z) + ir.z * (rh.z * it.z - ih.z * rt.z);
    float a3 = rr.w * (rh.w * rt.w + ih.w * it.w) + ir.w * (rh.w * it.w - ih.w * rt.w);
    float acc = (a0 + a1) + (a2 + a3);

    #pragma unroll
    for (int off = 16; off > 0; off >>= 1)
        acc += __shfl_xor(acc, off, 32);

    if (lane == 0)
        out[edge] = acc;
}

extern "C" void kernel_launch(void* const* d_in, const int* in_sizes, int n_in,
                              void* d_out, int out_size, void* d_ws, size_t ws_size,
                              hipStream_t stream) {
    const float* node_emb = (const float*)d_in[0];
    const float* rel_emb  = (const float*)d_in[1];
    const int*   src      = (const int*)d_in[2];
    const int*   dst      = (const int*)d_in[3];
    const int*   rel_id   = (const int*)d_in[4];
    float* out = (float*)d_out;

    const int n_edges = in_sizes[2];            // 400000
    const int n_nodes = in_sizes[0] / DIM;      // 100000
    const int n_rels  = in_sizes[1] / DIM;      // 1000

    const size_t f16_bytes = ((size_t)n_nodes + (size_t)n_rels) * DIM * 2;

    const int tpb = 256;
    const long long total_threads = (long long)n_edges * 32;
    const int score_blocks = (int)((total_threads + tpb - 1) / tpb);

    if (ws_size >= f16_bytes) {
        __half* node_f16 = (__half*)d_ws;
        __half* rel_f16  = node_f16 + (size_t)n_nodes * DIM;

        const int node_threads = n_nodes * 32;
        const int rel_threads  = n_rels * 32;

        f32_to_f16i_kernel<<<(node_threads + tpb - 1) / tpb, tpb, 0, stream>>>(
            node_emb, (int4*)node_f16, n_nodes);
        f32_to_f16i_kernel<<<(rel_threads + tpb - 1) / tpb, tpb, 0, stream>>>(
            rel_emb, (int4*)rel_f16, n_rels);

        complex_score_f16i_kernel<<<score_blocks, tpb, 0, stream>>>(
            node_f16, rel_f16, src, dst, rel_id, out, n_edges);
    } else {
        complex_score_f32_kernel<<<score_blocks, tpb, 0, stream>>>(
            node_emb, rel_emb, src, dst, rel_id, out, n_edges);
    }
}

// Round 9
// 218.899 us; speedup vs baseline: 1.0494x; 1.0494x over previous
//
#include <hip/hip_runtime.h>
#include <hip/hip_fp16.h>
#include <string.h>

#define DIM 256

typedef __attribute__((ext_vector_type(2))) _Float16 half2v;

#if defined(__has_builtin)
#if __has_builtin(__builtin_amdgcn_fdot2)
#define HAVE_FDOT2 1
#endif
#endif

// ---------- merged fp32 -> fp16 pair-interleave compression (node + rel) -------
// Row layout out: pair j at halves [2j,2j+1] = (in[j], in[j+128]).
// 32 threads per row; thread q reads float4 from real half [4q..4q+4) and
// float4 from imag half [128+4q..), writes one int4 (4 half2 pairs).
// Rows [0, n_node) come from node table, rows [n_node, n_total) from rel table.
__global__ __launch_bounds__(256) void compress_f16i_kernel(
    const float* __restrict__ node, const float* __restrict__ rel,
    int4* __restrict__ out, int n_node, int n_total)
{
    int i = blockIdx.x * blockDim.x + threadIdx.x;
    int row = i >> 5;
    int q   = i & 31;
    if (row >= n_total) return;

    const float* base = (row < n_node)
        ? (node + (size_t)row * DIM)
        : (rel + (size_t)(row - n_node) * DIM);

    float4 a = *((const float4*)base + q);
    float4 b = *((const float4*)(base + 128) + q);

    __half2 p0 = __float22half2_rn(make_float2(a.x, b.x));
    __half2 p1 = __float22half2_rn(make_float2(a.y, b.y));
    __half2 p2 = __float22half2_rn(make_float2(a.z, b.z));
    __half2 p3 = __float22half2_rn(make_float2(a.w, b.w));

    int4 o;
    memcpy(&o.x, &p0, 4);
    memcpy(&o.y, &p1, 4);
    memcpy(&o.z, &p2, 4);
    memcpy(&o.w, &p3, 4);
    out[(size_t)row * 32 + q] = o;
}

// ---------- per-pair score term ------------------------------------------------
// h2=(rh,ih), t2=(rt,it), r2=(rr,ir), all fp16 pairs in one u32.
//   u = rr*rt + ir*it = dot2(r2, t2);  v = rr*it - ir*rt = dot2(r2, (it,-rt))
//   acc += rh*u + ih*v
__device__ __forceinline__ float pair_term(int h32, int t32, int r32, float acc)
{
    unsigned tu = (unsigned)t32;
    unsigned tsw = (tu >> 16) | ((tu << 16) ^ 0x80000000u);  // (it, -rt)

    half2v h2, t2, r2, ts2;
    memcpy(&h2, &h32, 4);
    memcpy(&t2, &t32, 4);
    memcpy(&r2, &r32, 4);
    memcpy(&ts2, &tsw, 4);

#ifdef HAVE_FDOT2
    float u = __builtin_amdgcn_fdot2(r2, t2, 0.0f, false);
    float v = __builtin_amdgcn_fdot2(r2, ts2, 0.0f, false);
#else
    float rr = (float)r2.x, ir = (float)r2.y;
    float rt = (float)t2.x, it = (float)t2.y;
    float u = rr * rt + ir * it;
    float v = rr * it - ir * rt;
    (void)ts2;
#endif
    float rh = (float)h2.x;
    float ih = (float)h2.y;
    acc = fmaf(rh, u, acc);
    acc = fmaf(ih, v, acc);
    return acc;
}

// ---------- score kernel: 2 edges per 32-lane group (2x memory-level par.) -----
// Group g handles edges g and g+half_edges. All 6 row-gathers are issued
// before any compute so up to 6x512B are in flight per group.
__global__ __launch_bounds__(256) void complex_score_f16i2_kernel(
    const __half* __restrict__ node,
    const __half* __restrict__ rel,
    const int* __restrict__ src,
    const int* __restrict__ dst,
    const int* __restrict__ rid,
    float* __restrict__ out,
    int n_edges, int half_edges)
{
    const int tid  = blockIdx.x * blockDim.x + threadIdx.x;
    const int g    = tid >> 5;
    const int lane = tid & 31;
    if (g >= half_edges) return;

    const int e0 = g;
    const int e1 = g + half_edges;
    const bool have1 = (e1 < n_edges);

    const int s0 = src[e0], d0 = dst[e0], r0 = rid[e0];
    int s1 = s0, d1 = d0, r1 = r0;
    if (have1) { s1 = src[e1]; d1 = dst[e1]; r1 = rid[e1]; }

    const int4* np = (const int4*)node;
    const int4* rp = (const int4*)rel;

    // issue all six row loads
    int4 h0 = np[(size_t)s0 * 32 + lane];
    int4 t0 = np[(size_t)d0 * 32 + lane];
    int4 v0 = rp[(size_t)r0 * 32 + lane];
    int4 h1 = np[(size_t)s1 * 32 + lane];
    int4 t1 = np[(size_t)d1 * 32 + lane];
    int4 v1 = rp[(size_t)r1 * 32 + lane];

    float acc0 = 0.0f;
    acc0 = pair_term(h0.x, t0.x, v0.x, acc0);
    acc0 = pair_term(h0.y, t0.y, v0.y, acc0);
    acc0 = pair_term(h0.z, t0.z, v0.z, acc0);
    acc0 = pair_term(h0.w, t0.w, v0.w, acc0);

    float acc1 = 0.0f;
    acc1 = pair_term(h1.x, t1.x, v1.x, acc1);
    acc1 = pair_term(h1.y, t1.y, v1.y, acc1);
    acc1 = pair_term(h1.z, t1.z, v1.z, acc1);
    acc1 = pair_term(h1.w, t1.w, v1.w, acc1);

    #pragma unroll
    for (int off = 16; off > 0; off >>= 1) {
        acc0 += __shfl_xor(acc0, off);
        acc1 += __shfl_xor(acc1, off);
    }

    if (lane == 0) {
        out[e0] = acc0;
        if (have1) out[e1] = acc1;
    }
}

// ---------- fallback: direct fp32 path (if ws is too small) --------------------
__global__ __launch_bounds__(256) void complex_score_f32_kernel(
    const float* __restrict__ node_emb,
    const float* __restrict__ rel_emb,
    const int* __restrict__ src,
    const int* __restrict__ dst,
    const int* __restrict__ rel_id,
    float* __restrict__ out,
    int n_edges)
{
    const int tid  = blockIdx.x * blockDim.x + threadIdx.x;
    const int edge = tid >> 5;
    const int lane = tid & 31;
    if (edge >= n_edges) return;

    const int s = src[edge];
    const int d = dst[edge];
    const int r = rel_id[edge];

    const float4* hp = (const float4*)(node_emb + (size_t)s * DIM);
    const float4* tp = (const float4*)(node_emb + (size_t)d * DIM);
    const float4* rp = (const float4*)(rel_emb  + (size_t)r * DIM);

    float4 rh = hp[lane];
    float4 ih = hp[lane + 32];
    float4 rt = tp[lane];
    float4 it = tp[lane + 32];
    float4 rr = rp[lane];
    float4 ir = rp[lane + 32];

    float a0 = rr.x * (rh.x * rt.x + ih.x * it.x) + ir.x * (rh.x * it.x - ih.x * rt.x);
    float a1 = rr.y * (rh.y * rt.y + ih.y * it.y) + ir.y * (rh.y * it.y - ih.y * rt.y);
    float a2 = rr.z * (rh.z * rt.z + ih.z * it.z) + ir.z * (rh.z * it.z - ih.z * rt.z);
    float a3 = rr.w * (rh.w * rt.w + ih.w * it.w) + ir.w * (rh.w * it.w - ih.w * rt.w);
    float acc = (a0 + a1) + (a2 + a3);

    #pragma unroll
    for (int off = 16; off > 0; off >>= 1)
        acc += __shfl_xor(acc, off, 32);

    if (lane == 0)
        out[edge] = acc;
}

extern "C" void kernel_launch(void* const* d_in, const int* in_sizes, int n_in,
                              void* d_out, int out_size, void* d_ws, size_t ws_size,
                              hipStream_t stream) {
    const float* node_emb = (const float*)d_in[0];
    const float* rel_emb  = (const float*)d_in[1];
    const int*   src      = (const int*)d_in[2];
    const int*   dst      = (const int*)d_in[3];
    const int*   rel_id   = (const int*)d_in[4];
    float* out = (float*)d_out;

    const int n_edges = in_sizes[2];            // 400000
    const int n_nodes = in_sizes[0] / DIM;      // 100000
    const int n_rels  = in_sizes[1] / DIM;      // 1000

    const size_t f16_bytes = ((size_t)n_nodes + (size_t)n_rels) * DIM * 2;
    const int tpb = 256;

    if (ws_size >= f16_bytes) {
        __half* node_f16 = (__half*)d_ws;
        __half* rel_f16  = node_f16 + (size_t)n_nodes * DIM;

        const int n_total_rows = n_nodes + n_rels;
        const long long comp_threads = (long long)n_total_rows * 32;
        compress_f16i_kernel<<<(int)((comp_threads + tpb - 1) / tpb), tpb, 0, stream>>>(
            node_emb, rel_emb, (int4*)d_ws, n_nodes, n_total_rows);

        const int half_edges = (n_edges + 1) / 2;
        const long long score_threads = (long long)half_edges * 32;
        complex_score_f16i2_kernel<<<(int)((score_threads + tpb - 1) / tpb), tpb, 0, stream>>>(
            node_f16, rel_f16, src, dst, rel_id, out, n_edges, half_edges);
    } else {
        const long long total_threads = (long long)n_edges * 32;
        complex_score_f32_kernel<<<(int)((total_threads + tpb - 1) / tpb), tpb, 0, stream>>>(
            node_emb, rel_emb, src, dst, rel_id, out, n_edges);
    }
}